// Round 1
// baseline (91.996 us; speedup 1.0000x reference)
//
#include <hip/hip_runtime.h>
#include <math.h>

#define BB 256
#define CC 28
#define DD 2048
#define KK 16

// ---------------------------------------------------------------------------
// k_select: one block (1 wave = 64 lanes) per class c.
//  - counts[c] = number of positives
//  - Nlist[c][0..15]: indices of top-16 negatives by descending inp (tie -> smaller idx)
//  - nn_arr[c] = number of valid (finite) entries in Nlist (min(16, #neg))
//  - Slist[c][0..16]: positives sorted ascending by inp (tie -> smaller idx), K+1 entries
//  - Plist[c][0..15]: positive indices in index order (minority classes have m <= 14)
// Exactly replicates jax.lax.top_k tie-breaking (stable, smaller index wins).
// ---------------------------------------------------------------------------
__global__ __launch_bounds__(64) void k_select(const float* __restrict__ inp,
                                               const int* __restrict__ target,
                                               int* __restrict__ counts,
                                               int* __restrict__ nn_arr,
                                               int* __restrict__ Nlist,
                                               int* __restrict__ Slist,
                                               int* __restrict__ Plist,
                                               float* __restrict__ acc) {
  const int c = blockIdx.x;
  const int lane = threadIdx.x;  // 0..63
  if (c == 0 && lane == 0) { acc[0] = 0.f; acc[1] = 0.f; }

  float v[4];
  int pos[4];
#pragma unroll
  for (int q = 0; q < 4; ++q) {
    const int i = lane + 64 * q;
    v[q] = inp[i * CC + c];
    pos[q] = target[i * CC + c];
  }

  // m = #positives (wave sum)
  int m = pos[0] + pos[1] + pos[2] + pos[3];
#pragma unroll
  for (int s = 1; s < 64; s <<= 1) m += __shfl_xor(m, s);

  // ---- negative top-K: largest value first, ties -> smaller index ----
  float key[4];
#pragma unroll
  for (int q = 0; q < 4; ++q) key[q] = pos[q] ? -INFINITY : v[q];
  int n_n = 0;
  for (int t = 0; t < KK; ++t) {
    float bv = -INFINITY;
    int bi = 0x7fffffff;
#pragma unroll
    for (int q = 0; q < 4; ++q) {
      const int idx = lane + 64 * q;
      if (key[q] > bv || (key[q] == bv && idx < bi)) { bv = key[q]; bi = idx; }
    }
#pragma unroll
    for (int s = 1; s < 64; s <<= 1) {
      const float ov = __shfl_xor(bv, s);
      const int oi = __shfl_xor(bi, s);
      if (ov > bv || (ov == bv && oi < bi)) { bv = ov; bi = oi; }
    }
    if (bv > -1e30f) n_n++;          // finite => a real negative
    if (lane == 0) Nlist[c * KK + t] = bi;
    if ((bi & 63) == lane) key[bi >> 6] = -INFINITY;  // mask winner
  }

  // ---- positives sorted ascending: smallest value first, ties -> smaller index ----
#pragma unroll
  for (int q = 0; q < 4; ++q) key[q] = pos[q] ? v[q] : INFINITY;
  for (int t = 0; t < KK + 1; ++t) {
    float bv = INFINITY;
    int bi = 0x7fffffff;
#pragma unroll
    for (int q = 0; q < 4; ++q) {
      const int idx = lane + 64 * q;
      if (key[q] < bv || (key[q] == bv && idx < bi)) { bv = key[q]; bi = idx; }
    }
#pragma unroll
    for (int s = 1; s < 64; s <<= 1) {
      const float ov = __shfl_xor(bv, s);
      const int oi = __shfl_xor(bi, s);
      if (ov < bv || (ov == bv && oi < bi)) { bv = ov; bi = oi; }
    }
    if (lane == 0) Slist[c * (KK + 1) + t] = bi;
    if ((bi & 63) == lane) key[bi >> 6] = INFINITY;
  }

  if (lane == 0) { counts[c] = m; nn_arr[c] = n_n; }

  // ---- P list: positive indices in ascending index order (first 16) ----
  int cnt = 0;
#pragma unroll
  for (int q = 0; q < 4; ++q) {
    unsigned long long bm = __ballot(pos[q] != 0);  // convergent, all lanes
    if (lane == 0) {
      while (bm != 0ULL && cnt < KK) {
        const int b = __builtin_ctzll(bm);
        Plist[c * KK + cnt] = 64 * q + b;
        cnt++;
        bm &= bm - 1ULL;
      }
    }
  }
}

// ---------------------------------------------------------------------------
// k_dist: block (c, a) handles anchor slot a of class c (only minority classes
// with a < m are active; minority => m <= 14). Computes
//   dp_i = sum over first min(K, m-1) of (sorted positives \ {i}) of L1(X_i, X_j)
//   dn_i = sum over valid negatives of L1(X_i, X_j)
// and atomically accumulates n_n*dp_i into acc[0], n_p*dn_i into acc[1].
// ---------------------------------------------------------------------------
__global__ __launch_bounds__(256) void k_dist(const float* __restrict__ X,
                                              const int* __restrict__ counts,
                                              const int* __restrict__ nn_arr,
                                              const int* __restrict__ Nlist,
                                              const int* __restrict__ Slist,
                                              const int* __restrict__ Plist,
                                              float* __restrict__ acc) {
  const int c = blockIdx.x;
  const int a = blockIdx.y;
  const int tid = threadIdx.x;

  __shared__ float xi[DD];
  __shared__ int s_min;

  if (tid == 0) {
    // minority(c): stable-argsort cumsum rule, lexicographic on (count, index)
    const int mc = counts[c];
    int cum = 0;
    for (int c2 = 0; c2 < CC; ++c2) {
      const int m2 = counts[c2];
      if (m2 < mc || (m2 == mc && c2 <= c)) cum += m2;
    }
    s_min = (2 * cum <= CC) && (mc > 1);  // cum <= 0.5*NUM_CLASSES, counts > 1
  }
  __syncthreads();

  const int m = counts[c];
  if (!s_min || a >= m || a >= KK) return;

  const int i = Plist[c * KK + a];

  // stage anchor row in LDS (8 KB), coalesced float4
  for (int t = tid; t < DD / 4; t += 256)
    ((float4*)xi)[t] = ((const float4*)(X + (size_t)i * DD))[t];
  __syncthreads();

  const int wave = tid >> 6;
  const int lane = tid & 63;
  const int n_n = nn_arr[c];
  const int n_p = min(KK, m - 1);

  float dp_sum = 0.f, dn_sum = 0.f;
  for (int p = wave; p < n_p + n_n; p += 4) {
    const bool isdp = (p < n_p);
    int j;
    if (isdp) {
      // p-th element of (sorted positives S) \ {i}
      int want = p, c2 = 0;
      j = -1;
      for (int t = 0; t < KK + 1; ++t) {
        const int s = Slist[c * (KK + 1) + t];
        if (s == i) continue;
        if (c2 == want) { j = s; break; }
        c2++;
      }
    } else {
      j = Nlist[c * KK + (p - n_p)];
    }

    const float4* xj = (const float4*)(X + (size_t)j * DD);
    float partial = 0.f;
#pragma unroll
    for (int k = 0; k < 8; ++k) {
      const float4 b4 = xj[k * 64 + lane];
      const float4 a4 = ((const float4*)xi)[k * 64 + lane];
      partial += fabsf(a4.x - b4.x) + fabsf(a4.y - b4.y) +
                 fabsf(a4.z - b4.z) + fabsf(a4.w - b4.w);
    }
#pragma unroll
    for (int s = 1; s < 64; s <<= 1) partial += __shfl_xor(partial, s);

    if (isdp) dp_sum += partial; else dn_sum += partial;
  }

  if (lane == 0) {
    atomicAdd(&acc[0], (float)n_n * dp_sum);
    atomicAdd(&acc[1], (float)n_p * dn_sum);
  }
}

__global__ void k_final(const float* __restrict__ acc, float* __restrict__ out) {
  out[0] = fmaxf(acc[0] - acc[1] + 1.0f, 0.0f);
}

extern "C" void kernel_launch(void* const* d_in, const int* in_sizes, int n_in,
                              void* d_out, int out_size, void* d_ws, size_t ws_size,
                              hipStream_t stream) {
  (void)in_sizes; (void)n_in; (void)out_size; (void)ws_size;
  const float* inp   = (const float*)d_in[0];   // [256,28] f32
  const int*   target = (const int*)d_in[1];    // [256,28] i32
  const float* X     = (const float*)d_in[2];   // [256,2048] f32
  float* out = (float*)d_out;

  // workspace carve-up (~6 KB)
  float* acc    = (float*)d_ws;          // [2] dps_total, dns_total
  int*   counts = (int*)d_ws + 2;        // [28]
  int*   nn_arr = counts + CC;           // [28]
  int*   Nlist  = nn_arr + CC;           // [28][16]
  int*   Slist  = Nlist + CC * KK;       // [28][17]
  int*   Plist  = Slist + CC * (KK + 1); // [28][16]

  k_select<<<CC, 64, 0, stream>>>(inp, target, counts, nn_arr, Nlist, Slist, Plist, acc);
  k_dist<<<dim3(CC, KK), 256, 0, stream>>>(X, counts, nn_arr, Nlist, Slist, Plist, acc);
  k_final<<<1, 1, 0, stream>>>(acc, out);
}

// Round 3
// 72.340 us; speedup vs baseline: 1.2717x; 1.2717x over previous
//
#include <hip/hip_runtime.h>
#include <math.h>

typedef unsigned long long u64;
typedef unsigned int u32;

#define BB 256
#define CC 28
#define DD 2048
#define KK 16

// ---------------------------------------------------------------------------
// k_main: block (c, a) = class c, anchor-slot a. Every block redundantly
// computes per-class counts (ballot over coalesced target rows) and the
// minority mask in-register. Active blocks (minority class, a < m) select
// hardest negatives/positives with u64-packed keys (value bits || tiebreak)
// and compute the weighted L1 distance sums for their anchor. Every block
// unconditionally writes its partial pair to part[] (no zero-init needed,
// no atomics, deterministic).
// ---------------------------------------------------------------------------
__global__ __launch_bounds__(256) void k_main(const float* __restrict__ inp,
                                              const int* __restrict__ target,
                                              const float* __restrict__ X,
                                              float* __restrict__ part) {
  const int c = blockIdx.x;
  const int a = blockIdx.y;
  const int tid = threadIdx.x;
  const int wave = tid >> 6, lane = tid & 63;

  __shared__ u32 posbits[BB];       // row -> 28-bit positive mask
  __shared__ int s_cw[4][CC];       // per-wave per-class counts
  __shared__ int s_counts[CC];
  __shared__ int s_N[KK];           // hardest-negative rows (desc prob)
  __shared__ int s_S[KK + 2];       // positives sorted asc by prob
  __shared__ int s_anchor;
  __shared__ float s_red[8];

  // --- per-row positive bitmask: thread tid owns row tid (coalesced int4) ---
  u32 pb = 0;
  const int4* t4 = (const int4*)(target + tid * CC);
#pragma unroll
  for (int k = 0; k < 7; ++k) {
    int4 w = t4[k];
    pb |= (u32)(w.x != 0) << (4 * k) | (u32)(w.y != 0) << (4 * k + 1) |
          (u32)(w.z != 0) << (4 * k + 2) | (u32)(w.w != 0) << (4 * k + 3);
  }
  posbits[tid] = pb;

  // --- per-class counts via ballot ---
#pragma unroll
  for (int c2 = 0; c2 < CC; ++c2) {
    u64 b = __ballot((pb >> c2) & 1u);
    if (lane == 0) s_cw[wave][c2] = __popcll(b);
  }
  __syncthreads();
  if (tid < CC)
    s_counts[tid] = s_cw[0][tid] + s_cw[1][tid] + s_cw[2][tid] + s_cw[3][tid];
  __syncthreads();

  const int m = s_counts[c];
  // minority(c): stable-argsort cumsum rule, lexicographic on (count, index)
  int cum = 0;
#pragma unroll
  for (int c2 = 0; c2 < CC; ++c2) {
    const int m2 = s_counts[c2];
    if (m2 < m || (m2 == m && c2 <= c)) cum += m2;
  }
  const bool active = (2 * cum <= CC) && (m > 1) && (a < m) && (a < KK);
  if (!active) {  // block-uniform: safe early return
    if (tid == 0) { part[2 * (c * KK + a)] = 0.f; part[2 * (c * KK + a) + 1] = 0.f; }
    return;
  }

  const int mS = min(m, KK + 1);     // positives to extract (m <= 14 here)
  const int NP = min(KK, m - 1);     // valid positives per anchor
  const int NN = min(KK, BB - m);    // valid negatives (= 16 here)

  // --- selection: wave 0 = negatives (desc), wave 1 = positives (asc),
  //     wave 2 = anchor row (a-th positive in row order) ---
  if (wave == 0) {
    // key = (float bits << 32) | (~row): argmax = largest value, tie smaller row
    u64 kn[4];
#pragma unroll
    for (int q = 0; q < 4; ++q) {
      const int row = lane + 64 * q;
      const float val = inp[row * CC + c];
      const int p = (posbits[row] >> c) & 1;
      kn[q] = p ? 0ull
                : (((u64)__float_as_uint(val)) << 32) | (u64)(0xFFFFFFFFu - row);
    }
    for (int t = 0; t < KK; ++t) {
      u64 b = kn[0];
#pragma unroll
      for (int q = 1; q < 4; ++q) b = kn[q] > b ? kn[q] : b;
#pragma unroll
      for (int s = 1; s < 64; s <<= 1) {
        const u64 o = __shfl_xor(b, s);
        b = o > b ? o : b;
      }
      const int row = (int)(0xFFFFFFFFu - (u32)b);
      if (lane == 0) s_N[t] = row;
      if ((row & 63) == lane) kn[row >> 6] = 0ull;  // mask winner
    }
  } else if (wave == 1) {
    // key = (float bits << 32) | row: argmin = smallest value, tie smaller row
    u64 kp[4];
#pragma unroll
    for (int q = 0; q < 4; ++q) {
      const int row = lane + 64 * q;
      const float val = inp[row * CC + c];
      const int p = (posbits[row] >> c) & 1;
      kp[q] = p ? (((u64)__float_as_uint(val)) << 32) | (u64)row
                : 0xFFFFFFFFFFFFFFFFull;
    }
    for (int t = 0; t < mS; ++t) {
      u64 b = kp[0];
#pragma unroll
      for (int q = 1; q < 4; ++q) b = kp[q] < b ? kp[q] : b;
#pragma unroll
      for (int s = 1; s < 64; s <<= 1) {
        const u64 o = __shfl_xor(b, s);
        b = o < b ? o : b;
      }
      const int row = (int)(u32)(b & 0xFFFFFFFFull);
      if (lane == 0) s_S[t] = row;
      if ((row & 63) == lane) kp[row >> 6] = 0xFFFFFFFFFFFFFFFFull;
    }
  } else if (wave == 2) {
    // a-th positive of class c in row order, via lane prefix-sum
    int sel[4], lc = 0;
#pragma unroll
    for (int q = 0; q < 4; ++q) {
      sel[q] = (posbits[4 * lane + q] >> c) & 1;
      lc += sel[q];
    }
    int pre = lc;
#pragma unroll
    for (int s = 1; s < 64; s <<= 1) {
      const int o = __shfl_up(pre, s);
      if (lane >= s) pre += o;
    }
    const int ex = pre - lc;  // exclusive prefix
    if (a >= ex && a < ex + lc) {
      int need = a - ex;
#pragma unroll
      for (int q = 0; q < 4; ++q) {
        if (sel[q]) {
          if (need == 0) s_anchor = 4 * lane + q;
          need--;
        }
      }
    }
  }
  __syncthreads();

  const int anchor = s_anchor;
  // position of anchor within sorted-positive list (for exclusion)
  int idx_a = 0;
  for (int t = 0; t < mS; ++t)
    if (s_S[t] == anchor) idx_a = t;

  // anchor row in registers: 8 float4 per lane, coalesced
  const float4* Xa = (const float4*)(X + (size_t)anchor * DD);
  float4 A[8];
#pragma unroll
  for (int q = 0; q < 8; ++q) A[q] = Xa[q * 64 + lane];

  // --- distances: waves split the <=29 partner rows ---
  float dpw = 0.f, dnw = 0.f;
  for (int p = wave; p < NP + NN; p += 4) {
    const bool isdp = (p < NP);
    const int j = isdp ? s_S[p + (p >= idx_a ? 1 : 0)] : s_N[p - NP];
    const float4* Xj = (const float4*)(X + (size_t)j * DD);
    float partial = 0.f;
#pragma unroll
    for (int q = 0; q < 8; ++q) {
      const float4 b4 = Xj[q * 64 + lane];
      partial += fabsf(A[q].x - b4.x) + fabsf(A[q].y - b4.y) +
                 fabsf(A[q].z - b4.z) + fabsf(A[q].w - b4.w);
    }
#pragma unroll
    for (int s = 1; s < 64; s <<= 1) partial += __shfl_xor(partial, s);
    if (isdp) dpw += partial; else dnw += partial;
  }
  if (lane == 0) { s_red[2 * wave] = dpw; s_red[2 * wave + 1] = dnw; }
  __syncthreads();

  if (tid == 0) {
    const float dp = s_red[0] + s_red[2] + s_red[4] + s_red[6];
    const float dn = s_red[1] + s_red[3] + s_red[5] + s_red[7];
    part[2 * (c * KK + a)] = (float)NN * dp;      // each positive in n_n triplets
    part[2 * (c * KK + a) + 1] = (float)NP * dn;  // each negative in n_p triplets
  }
}

// ---------------------------------------------------------------------------
// k_final: sum the 448 partial pairs, apply margin + relu.
// ---------------------------------------------------------------------------
__global__ __launch_bounds__(256) void k_final(const float* __restrict__ part,
                                               float* __restrict__ out) {
  const int tid = threadIdx.x;
  const int wave = tid >> 6, lane = tid & 63;
  __shared__ float s_red[8];

  float dp = 0.f, dn = 0.f;
  for (int t = tid; t < CC * KK; t += 256) {
    dp += part[2 * t];
    dn += part[2 * t + 1];
  }
#pragma unroll
  for (int s = 1; s < 64; s <<= 1) {
    dp += __shfl_xor(dp, s);
    dn += __shfl_xor(dn, s);
  }
  if (lane == 0) { s_red[2 * wave] = dp; s_red[2 * wave + 1] = dn; }
  __syncthreads();
  if (tid == 0) {
    const float dpT = s_red[0] + s_red[2] + s_red[4] + s_red[6];
    const float dnT = s_red[1] + s_red[3] + s_red[5] + s_red[7];
    out[0] = fmaxf(dpT - dnT + 1.0f, 0.0f);
  }
}

extern "C" void kernel_launch(void* const* d_in, const int* in_sizes, int n_in,
                              void* d_out, int out_size, void* d_ws, size_t ws_size,
                              hipStream_t stream) {
  (void)in_sizes; (void)n_in; (void)out_size; (void)ws_size;
  const float* inp    = (const float*)d_in[0];  // [256,28] f32
  const int*   target = (const int*)d_in[1];    // [256,28] i32
  const float* X      = (const float*)d_in[2];  // [256,2048] f32
  float* out = (float*)d_out;
  float* part = (float*)d_ws;                   // [448][2] partials

  k_main<<<dim3(CC, KK), 256, 0, stream>>>(inp, target, X, part);
  k_final<<<1, 256, 0, stream>>>(part, out);
}